// Round 6
// baseline (398.901 us; speedup 1.0000x reference)
//
#include <hip/hip_runtime.h>
#include <limits.h>

#define N_PTS   200000
#define N_EDGES 1600000
#define MEM_SIZE (1 << 27)

#define COPY_BLOCKS  32768                    // 33,554,432 float4 / (256 thr * 4 per thr)
#define F4_PER_BLOCK 1024
#define EPB ((N_EDGES + COPY_BLOCKS - 1) / COPY_BLOCKS)   // 49 edges per block
#define NSHARD 16

// pair[s*N_PTS+n] = (min2 << 32) | min1 of half-edge indices seen by shard s.
// Sentinel: anything >= 2*N_EDGES is "absent". 16 shards dilute coherent-op
// traffic per cacheline ~16x (per-line RMW serialization was the round-5 wall).
__global__ void init_pairs(unsigned long long* __restrict__ pair) {
    int n = blockIdx.x * blockDim.x + threadIdx.x;
    if (n < NSHARD * N_PTS) pair[n] = 0xFFFFFFFFFFFFFFFFULL;
}

__device__ __forceinline__ void insert_pair(unsigned long long* p, unsigned int i) {
    // Plain (cacheable) fast-path load: within this kernel any stale value is
    // >= truth (values only decrease), so skipping when i >= stale m2 is
    // conservative; the CAS validates against the coherent copy.
    unsigned long long old = *p;
    while (true) {
        unsigned int m1 = (unsigned int)(old & 0xFFFFFFFFu);
        unsigned int m2 = (unsigned int)(old >> 32);
        if (i >= m2) return;                              // no change
        unsigned long long nv = (i < m1)
            ? (((unsigned long long)m1 << 32) | i)        // (i, m1)
            : (((unsigned long long)i  << 32) | m1);      // (m1, i)
        unsigned long long prev = atomicCAS(p, old, nv);
        if (prev == old) return;
        old = prev;
    }
}

// Copy + edge CAS interleaved WITHIN every block: copy loads issue first
// (HBM-bound), the ~49 edge lanes' CAS latency hides under them, stores last.
__global__ void fused_copy_edges(const float4* __restrict__ src, float4* __restrict__ dst,
                                 const int2* __restrict__ edges,
                                 unsigned long long* __restrict__ pair) {
    int b = blockIdx.x;
    int t = threadIdx.x;
    int base = b * F4_PER_BLOCK + t;

    float4 v0 = src[base];
    float4 v1 = src[base + 256];
    float4 v2 = src[base + 512];
    float4 v3 = src[base + 768];

    if (t < EPB) {
        int i = b * EPB + t;
        if (i < N_EDGES) {
            unsigned long long* shard = pair + (size_t)(b & (NSHARD - 1)) * N_PTS;
            int2 e = edges[i];
            insert_pair(&shard[e.x], (unsigned int)i);             // forward half-edge
            insert_pair(&shard[e.y], (unsigned int)(i + N_EDGES)); // reverse half-edge
        }
    }

    dst[base]       = v0;
    dst[base + 256] = v1;
    dst[base + 512] = v2;
    dst[base + 768] = v3;
}

__device__ __forceinline__ int quant6(float d) {
    // match jnp: clip(round((d + 1)/2 * 63), 0, 63); jnp.round = half-to-even -> rintf
    float x = ((d + 1.0f) / 2.0f) * 63.0f;
    float r = rintf(x);
    r = fminf(fmaxf(r, 0.0f), 63.0f);
    return (int)r;
}

__global__ void finalize(const float* __restrict__ pts, const float* __restrict__ tex,
                         const int2* __restrict__ edges,
                         const unsigned long long* __restrict__ pair,
                         float* __restrict__ out) {
    int n = blockIdx.x * blockDim.x + threadIdx.x;
    if (n >= N_PTS) return;

    // merge 16 per-shard (m1,m2) pairs -> global two smallest
    unsigned int k1 = 0xFFFFFFFFu, k2 = 0xFFFFFFFFu;
    #pragma unroll
    for (int s = 0; s < NSHARD; ++s) {
        unsigned long long pr = pair[(size_t)s * N_PTS + n];
        unsigned int m1 = (unsigned int)(pr & 0xFFFFFFFFu);
        unsigned int m2 = (unsigned int)(pr >> 32);
        if (m1 < k1) { k2 = k1; k1 = m1; } else if (m1 < k2) { k2 = m1; }
        if (m2 < k2 && m2 > k1) { k2 = m2; }   // m2 > m1 always; m2==k1 impossible (distinct indices)
    }

    float px = pts[2 * n], py = pts[2 * n + 1];
    int t = (tex[n] > 0.7f) ? 1 : 0;

    int v0x = 0, v0y = 0, t0 = 0, v1x = 0, v1y = 0, t1 = 0;

    if (k1 < 2u * N_EDGES) {
        int k = (int)k1;
        int2 e = edges[(k < N_EDGES) ? k : (k - N_EDGES)];
        int dst = (k < N_EDGES) ? e.y : e.x;
        v0x = quant6(pts[2 * dst] - px);
        v0y = quant6(pts[2 * dst + 1] - py);
        t0 = (tex[dst] > 0.7f) ? 1 : 0;
    }
    if (k2 < 2u * N_EDGES) {
        int k = (int)k2;
        int2 e = edges[(k < N_EDGES) ? k : (k - N_EDGES)];
        int dst = (k < N_EDGES) ? e.y : e.x;
        v1x = quant6(pts[2 * dst] - px);
        v1y = quant6(pts[2 * dst + 1] - py);
        t1 = (tex[dst] > 0.7f) ? 1 : 0;
    }

    // hash keeps only cols 0..4 (col4 masked to 3 bits); each rel-variant
    // appears 6 times in rel_all (2 builds x 3 identity-rolls / 3 swap-rolls).
    int h_id = t | (v0x << 6) | (v0y << 12) | (t0 << 18) | ((v1x & 7) << 24);
    int h_sw = t | (v1x << 6) | (v1y << 12) | (t1 << 18) | ((v0x & 7) << 24);

    atomicAdd(&out[h_id], 6.0f);
    atomicAdd(&out[h_sw], 6.0f);
}

extern "C" void kernel_launch(void* const* d_in, const int* in_sizes, int n_in,
                              void* d_out, int out_size, void* d_ws, size_t ws_size,
                              hipStream_t stream) {
    const float* pts   = (const float*)d_in[0];
    const float* tex   = (const float*)d_in[1];
    const int2*  edges = (const int2*)d_in[2];   // int64 in ref -> int32 on device
    const float* mem   = (const float*)d_in[3];
    float*       out   = (float*)d_out;

    unsigned long long* pair = (unsigned long long*)d_ws;

    const int B = 256;
    init_pairs<<<(NSHARD * N_PTS + B - 1) / B, B, 0, stream>>>(pair);
    fused_copy_edges<<<COPY_BLOCKS, B, 0, stream>>>(
        (const float4*)mem, (float4*)out, edges, pair);
    finalize<<<(N_PTS + B - 1) / B, B, 0, stream>>>(pts, tex, edges, pair, out);
}